// Round 4
// baseline (198.882 us; speedup 1.0000x reference)
//
#include <hip/hip_runtime.h>

#define B_    32
#define H_    640
#define W_    368
#define OH    634          // H - 6
#define OW    362          // W - 6
#define CHUNK 14           // output rows per wave (multiple of 7)
#define NSTRIPE 6          // ceil(362/64)
#define NCY   12           // 48 chunk-slots (46 valid)
#define NBLK  (NSTRIPE * NCY * B_)   // 2304 = 64 * 36
#define GROUPS 64
#define PER_GROUP (NBLK / GROUPS)    // 36

// d_ws layout (floats):
//   [0..31]      per-batch max of target (int-bits atomicMax; 0xAA poison is a negative
//                int, any positive-float bits win, so no pre-zeroing needed)
//   [64..1087]   64 partial-sum slots, stride 16 floats (64 B); zeroed by k_max blk 0
//   [1088..2111] 64 group counters (uint), stride 16; zeroed by k_max blk 0
//   [2112]       root counter (uint); zeroed by k_max blk 0
#define SLOT0 64
#define CNT0  1088
#define ROOTC 2112
#define STRIDE 16

typedef float f4 __attribute__((ext_vector_type(4)));
struct __attribute__((packed)) uf4 { f4 v; };   // align-4 16B load wrapper

__global__ __launch_bounds__(256) void k_max(const float* __restrict__ tgt,
                                             float* __restrict__ ws) {
    if (blockIdx.x == 0) {                     // zero scratch (stream order vs k_ssim)
        for (int i = threadIdx.x; i < 2 * GROUPS * STRIDE + STRIDE; i += 256)
            ws[SLOT0 + i] = 0.0f;              // covers slots + counters + root
    }
    const int b   = blockIdx.x >> 5;           // 32 segments per batch
    const int seg = blockIdx.x & 31;
    const int perseg = (H_ * W_) / 32;         // 7360 floats
    const float4* p = (const float4*)(tgt + (size_t)b * (H_ * W_) + (size_t)seg * perseg);
    const int n4 = perseg / 4;                 // 1840
    float m = 0.0f;
    for (int i = threadIdx.x; i < n4; i += 256) {
        float4 v = p[i];
        m = fmaxf(m, fmaxf(fmaxf(v.x, v.y), fmaxf(v.z, v.w)));
    }
    #pragma unroll
    for (int off = 32; off; off >>= 1)
        m = fmaxf(m, __shfl_down(m, off, 64));
    __shared__ float sm[4];
    const int lane = threadIdx.x & 63, wv = threadIdx.x >> 6;
    if (lane == 0) sm[wv] = m;
    __syncthreads();
    if (threadIdx.x == 0) {
        m = fmaxf(fmaxf(sm[0], sm[1]), fmaxf(sm[2], sm[3]));
        atomicMax((int*)ws + b, __float_as_int(m));   // inputs >= 0
    }
}

__device__ __forceinline__ void hsum7(const float* __restrict__ xr,
                                      const float* __restrict__ yr,
                                      float& hx, float& hy,
                                      float& hxx, float& hyy, float& hxy) {
    const f4 xa = ((const uf4*)(xr))->v;       // elems 0..3
    const f4 xb = ((const uf4*)(xr + 3))->v;   // elems 3..6
    const f4 ya = ((const uf4*)(yr))->v;
    const f4 yb = ((const uf4*)(yr + 3))->v;
    const float xs[7] = {xa.x, xa.y, xa.z, xb.x, xb.y, xb.z, xb.w};
    const float ys[7] = {ya.x, ya.y, ya.z, yb.x, yb.y, yb.z, yb.w};
    hx = 0; hy = 0; hxx = 0; hyy = 0; hxy = 0;
    #pragma unroll
    for (int k = 0; k < 7; ++k) {
        const float xv = xs[k], yv = ys[k];
        hx += xv; hy += yv;
        hxx = fmaf(xv, xv, hxx);
        hyy = fmaf(yv, yv, hyy);
        hxy = fmaf(xv, yv, hxy);
    }
}

__global__ __launch_bounds__(256) void k_ssim(const float* __restrict__ X,
                                              const float* __restrict__ Y,
                                              float* __restrict__ ws,
                                              float* __restrict__ out) {
    const int sx   = blockIdx.x;               // column stripe
    const int w    = threadIdx.x >> 6;         // wave within block
    const int lane = threadIdx.x & 63;
    const int b    = blockIdx.z;
    const int chunkIdx = blockIdx.y * 4 + w;   // 0..47 (46 valid)
    const int r0   = chunkIdx * CHUNK;
    const int c    = sx * 64 + lane;
    const int outRows = min(CHUNK, OH - r0);   // <=0 for invalid chunks
    const bool colOK = (c < OW);

    const float dr  = ws[b];
    float C1 = 0.01f * dr; C1 *= C1;
    float C2 = 0.03f * dr; C2 *= C2;
    const float c1s = C1 * 2401.0f;            // C1 * 49^2 (scaled-domain constants)
    const float c2s = C2 * 2401.0f;
    const float covn2 = 2.0f * (49.0f / 48.0f);
    const float covn  = 49.0f / 48.0f;

    const float* xb = X + (size_t)b * (H_ * W_);
    const float* yb = Y + (size_t)b * (H_ * W_);

    float acc = 0.0f;

    if (colOK && outRows > 0) {
        float rx[7], ry[7], rxx[7], ryy[7], rxy[7];
        float tx = 0, ty = 0, txx = 0, tyy = 0, txy = 0;

        #pragma unroll
        for (int p = 0; p < 6; ++p) {          // prime 6 halo rows
            float hx, hy, hxx, hyy, hxy;
            hsum7(xb + (size_t)(r0 + p) * W_ + c,
                  yb + (size_t)(r0 + p) * W_ + c, hx, hy, hxx, hyy, hxy);
            rx[p] = hx; ry[p] = hy; rxx[p] = hxx; ryy[p] = hyy; rxy[p] = hxy;
            tx += hx; ty += hy; txx += hxx; tyy += hyy; txy += hxy;
        }

        for (int ii = 0; ii < outRows; ii += 7) {
            #pragma unroll
            for (int p = 0; p < 7; ++p) {      // ring slots compile-time
                const int i = ii + p;
                if (i >= outRows) break;       // wave-uniform
                float hx, hy, hxx, hyy, hxy;
                hsum7(xb + (size_t)(r0 + i + 6) * W_ + c,
                      yb + (size_t)(r0 + i + 6) * W_ + c, hx, hy, hxx, hyy, hxy);
                tx += hx; ty += hy; txx += hxx; tyy += hyy; txy += hxy;

                // scaled-domain SSIM: all u* scales cancel in the ratio
                const float pxy = tx * ty;
                const float A1  = fmaf(pxy, 2.0f, c1s);            // 2*tx*ty + C1*49^2
                const float s2  = fmaf(tx, tx, ty * ty);           // tx^2 + ty^2
                const float B1  = s2 + c1s;
                const float mxy = fmaf(49.0f, txy, -pxy);          // 49*txy - tx*ty
                const float A2  = fmaf(covn2, mxy, c2s);
                const float vs  = fmaf(49.0f, txx + tyy, -s2);     // 49*(txx+tyy) - (tx^2+ty^2)
                const float B2  = fmaf(covn, vs, c2s);
                acc = fmaf(A1 * A2, __builtin_amdgcn_rcpf(B1 * B2), acc);

                tx -= rx[p]; ty -= ry[p]; txx -= rxx[p]; tyy -= ryy[p]; txy -= rxy[p];
                const int sn = (p + 6) % 7;
                rx[sn] = hx; ry[sn] = hy; rxx[sn] = hxx; ryy[sn] = hyy; rxy[sn] = hxy;
            }
        }
    }

    // wave reduce, then LDS reduce across the 4 waves, ONE atomic per block
    #pragma unroll
    for (int off = 32; off; off >>= 1)
        acc += __shfl_down(acc, off, 64);
    __shared__ float sm[4];
    if (lane == 0) sm[w] = acc;
    __syncthreads();
    if (threadIdx.x == 0) {
        const float s = (sm[0] + sm[1]) + (sm[2] + sm[3]);
        const int blk = (blockIdx.z * NCY + blockIdx.y) * NSTRIPE + blockIdx.x;
        const int g   = blk & (GROUPS - 1);
        float* slots = ws + SLOT0;
        atomicAdd(&slots[g * STRIDE], s);      // 64 independent cachelines
        __threadfence();
        unsigned* cnt1 = (unsigned*)(ws + CNT0);
        const unsigned d1 = atomicAdd(&cnt1[g * STRIDE], 1u);
        if (d1 == PER_GROUP - 1) {             // group g complete
            __threadfence();
            const unsigned d2 = atomicAdd((unsigned*)(ws + ROOTC), 1u);
            if (d2 == GROUPS - 1) {            // everything complete: finalize
                float tot = 0.0f;
                #pragma unroll
                for (int i = 0; i < GROUPS; ++i)
                    tot += atomicAdd(&slots[i * STRIDE], 0.0f);   // coherent read
                out[0] = 1.0f - tot * (1.0f / (32.0f * 634.0f * 362.0f));
            }
        }
    }
}

extern "C" void kernel_launch(void* const* d_in, const int* in_sizes, int n_in,
                              void* d_out, int out_size, void* d_ws, size_t ws_size,
                              hipStream_t stream) {
    const float* X = (const float*)d_in[0];   // 'output'
    const float* Y = (const float*)d_in[1];   // 'target'
    float* ws = (float*)d_ws;

    k_max<<<dim3(1024), dim3(256), 0, stream>>>(Y, ws);
    k_ssim<<<dim3(NSTRIPE, NCY, B_), dim3(256), 0, stream>>>(X, Y, ws, (float*)d_out);
}

// Round 5
// 173.631 us; speedup vs baseline: 1.1454x; 1.1454x over previous
//
#include <hip/hip_runtime.h>

#define B_    32
#define H_    640
#define W_    368
#define OH    634          // H - 6
#define OW    362          // W - 6
#define CHUNK 14           // output rows per block
#define NCHUNK 46          // ceil(634/14); last chunk has 4 rows
#define NBLK  (NCHUNK * B_)          // 1472 = 64 * 23
#define GROUPS 64
#define PER_GROUP (NBLK / GROUPS)    // 23

// d_ws layout (floats):
//   [0..31]      per-batch max of target (int-bits atomicMax; 0xAA poison is negative)
//   [64..1087]   64 partial-sum slots, stride 16 floats (64 B); zeroed by k_max blk 0
//   [1088..2111] 64 group counters (uint), stride 16; zeroed by k_max blk 0
//   [2112]       root counter (uint); zeroed by k_max blk 0
#define SLOT0 64
#define CNT0  1088
#define ROOTC 2112
#define STRIDE 16

typedef float f2 __attribute__((ext_vector_type(2)));

__global__ __launch_bounds__(256) void k_max(const float* __restrict__ tgt,
                                             float* __restrict__ ws) {
    if (blockIdx.x == 0) {                     // zero scratch (stream order vs k_ssim)
        for (int i = threadIdx.x; i < 2 * GROUPS * STRIDE + STRIDE; i += 256)
            ws[SLOT0 + i] = 0.0f;
    }
    const int b   = blockIdx.x >> 5;
    const int seg = blockIdx.x & 31;
    const int perseg = (H_ * W_) / 32;         // 7360 floats
    const float4* p = (const float4*)(tgt + (size_t)b * (H_ * W_) + (size_t)seg * perseg);
    const int n4 = perseg / 4;                 // 1840
    float m = 0.0f;
    for (int i = threadIdx.x; i < n4; i += 256) {
        float4 v = p[i];
        m = fmaxf(m, fmaxf(fmaxf(v.x, v.y), fmaxf(v.z, v.w)));
    }
    #pragma unroll
    for (int off = 32; off; off >>= 1)
        m = fmaxf(m, __shfl_down(m, off, 64));
    __shared__ float sm[4];
    const int lane = threadIdx.x & 63, wv = threadIdx.x >> 6;
    if (lane == 0) sm[wv] = m;
    __syncthreads();
    if (threadIdx.x == 0) {
        m = fmaxf(fmaxf(sm[0], sm[1]), fmaxf(sm[2], sm[3]));
        atomicMax((int*)ws + b, __float_as_int(m));   // inputs >= 0
    }
}

// Horizontal 7-sums for TWO adjacent windows (cols c..c+6 and c+1..c+7)
// from 8 floats loaded as 4 naturally-aligned float2 per array.
__device__ __forceinline__ void hsum2(const float* __restrict__ xr,
                                      const float* __restrict__ yr,
                                      float h[10]) {   // {x0,x1,y0,y1,xx0,xx1,yy0,yy1,xy0,xy1}
    const f2* xp = (const f2*)xr;   // 8-byte aligned: (r*368 + 2t)*4
    const f2* yp = (const f2*)yr;
    f2 xa = xp[0], xb = xp[1], xc = xp[2], xd = xp[3];
    f2 ya = yp[0], yb = yp[1], yc = yp[2], yd = yp[3];
    const float xs[8] = {xa.x, xa.y, xb.x, xb.y, xc.x, xc.y, xd.x, xd.y};
    const float ys[8] = {ya.x, ya.y, yb.x, yb.y, yc.x, yc.y, yd.x, yd.y};
    float hx = 0, hy = 0, hxx = 0, hyy = 0, hxy = 0;
    #pragma unroll
    for (int k = 0; k < 7; ++k) {
        const float xv = xs[k], yv = ys[k];
        hx += xv; hy += yv;
        hxx = fmaf(xv, xv, hxx);
        hyy = fmaf(yv, yv, hyy);
        hxy = fmaf(xv, yv, hxy);
    }
    h[0] = hx;  h[1] = hx - xs[0] + xs[7];
    h[2] = hy;  h[3] = hy - ys[0] + ys[7];
    h[4] = hxx; h[5] = fmaf(xs[7], xs[7], fmaf(-xs[0], xs[0], hxx));
    h[6] = hyy; h[7] = fmaf(ys[7], ys[7], fmaf(-ys[0], ys[0], hyy));
    h[8] = hxy; h[9] = fmaf(xs[7], ys[7], fmaf(-xs[0], ys[0], hxy));
}

__global__ __launch_bounds__(192) void k_ssim(const float* __restrict__ X,
                                              const float* __restrict__ Y,
                                              float* __restrict__ ws,
                                              float* __restrict__ out) {
    const int t    = threadIdx.x;              // 0..191
    const int w    = t >> 6;
    const int lane = t & 63;
    const int b    = blockIdx.y;
    const int r0   = blockIdx.x * CHUNK;
    const int outRows = min(CHUNK, OH - r0);   // >=4 always
    const int c    = 2 * t;                    // base output col
    const bool colOK = (c < OW);               // t <= 180

    const float dr  = ws[b];
    float C1 = 0.01f * dr; C1 *= C1;
    float C2 = 0.03f * dr; C2 *= C2;
    const float c1s = C1 * 2401.0f;            // scaled-domain constants (u* scale cancels)
    const float c2s = C2 * 2401.0f;
    const float covn2 = 2.0f * (49.0f / 48.0f);
    const float covn  = 49.0f / 48.0f;

    const float* xb = X + (size_t)b * (H_ * W_) + c;
    const float* yb = Y + (size_t)b * (H_ * W_) + c;

    float acc = 0.0f;

    if (colOK) {
        float ring[5][7][2];                   // [quantity][row slot][col]
        float tot[5][2] = {};
        float h[10];

        #pragma unroll
        for (int p = 0; p < 6; ++p) {          // prime 6 halo rows
            hsum2(xb + (size_t)(r0 + p) * W_, yb + (size_t)(r0 + p) * W_, h);
            #pragma unroll
            for (int q = 0; q < 5; ++q) {
                ring[q][p][0] = h[2 * q];     ring[q][p][1] = h[2 * q + 1];
                tot[q][0] += h[2 * q];        tot[q][1] += h[2 * q + 1];
            }
        }

        for (int ii = 0; ii < outRows; ii += 7) {
            #pragma unroll
            for (int p = 0; p < 7; ++p) {      // ring slots compile-time
                const int i = ii + p;
                if (i >= outRows) break;       // block-uniform
                hsum2(xb + (size_t)(r0 + i + 6) * W_, yb + (size_t)(r0 + i + 6) * W_, h);
                #pragma unroll
                for (int q = 0; q < 5; ++q) {
                    tot[q][0] += h[2 * q];    tot[q][1] += h[2 * q + 1];
                }

                #pragma unroll
                for (int j = 0; j < 2; ++j) {
                    const float tx = tot[0][j], ty = tot[1][j];
                    const float txx = tot[2][j], tyy = tot[3][j], txy = tot[4][j];
                    const float pxy = tx * ty;
                    const float A1  = fmaf(pxy, 2.0f, c1s);
                    const float s2  = fmaf(tx, tx, ty * ty);
                    const float B1  = s2 + c1s;
                    const float mxy = fmaf(49.0f, txy, -pxy);
                    const float A2  = fmaf(covn2, mxy, c2s);
                    const float vs  = fmaf(49.0f, txx + tyy, -s2);
                    const float B2  = fmaf(covn, vs, c2s);
                    acc = fmaf(A1 * A2, __builtin_amdgcn_rcpf(B1 * B2), acc);
                }

                const int sn = (p + 6) % 7;    // retire slot p, insert new in slot sn
                #pragma unroll
                for (int q = 0; q < 5; ++q) {
                    tot[q][0] -= ring[q][p][0];  tot[q][1] -= ring[q][p][1];
                    ring[q][sn][0] = h[2 * q];   ring[q][sn][1] = h[2 * q + 1];
                }
            }
        }
    }

    // wave reduce, then LDS across 3 waves, one scattered atomic per block
    #pragma unroll
    for (int off = 32; off; off >>= 1)
        acc += __shfl_down(acc, off, 64);
    __shared__ float sm[3];
    if (lane == 0) sm[w] = acc;
    __syncthreads();
    if (t == 0) {
        const float s = sm[0] + sm[1] + sm[2];
        const int blk = blockIdx.y * NCHUNK + blockIdx.x;
        const int g   = blk & (GROUPS - 1);
        float* slots = ws + SLOT0;
        atomicAdd(&slots[g * STRIDE], s);      // 64 independent cachelines
        __threadfence();
        unsigned* cnt1 = (unsigned*)(ws + CNT0);
        const unsigned d1 = atomicAdd(&cnt1[g * STRIDE], 1u);
        if (d1 == PER_GROUP - 1) {             // group complete
            __threadfence();
            const unsigned d2 = atomicAdd((unsigned*)(ws + ROOTC), 1u);
            if (d2 == GROUPS - 1) {            // all done: finalize
                float totsum = 0.0f;
                #pragma unroll
                for (int i = 0; i < GROUPS; ++i)
                    totsum += atomicAdd(&slots[i * STRIDE], 0.0f);
                out[0] = 1.0f - totsum * (1.0f / (32.0f * 634.0f * 362.0f));
            }
        }
    }
}

extern "C" void kernel_launch(void* const* d_in, const int* in_sizes, int n_in,
                              void* d_out, int out_size, void* d_ws, size_t ws_size,
                              hipStream_t stream) {
    const float* X = (const float*)d_in[0];   // 'output'
    const float* Y = (const float*)d_in[1];   // 'target'
    float* ws = (float*)d_ws;

    k_max<<<dim3(1024), dim3(256), 0, stream>>>(Y, ws);
    k_ssim<<<dim3(NCHUNK, B_), dim3(192), 0, stream>>>(X, Y, ws, (float*)d_out);
}

// Round 6
// 167.149 us; speedup vs baseline: 1.1899x; 1.0388x over previous
//
#include <hip/hip_runtime.h>

#define B_    32
#define H_    640
#define W_    368
#define OH    634          // H - 6
#define OW    362          // W - 6
#define CHUNK 10           // output rows per block
#define NCHUNK 64          // 63 full chunks + last (4 rows); 63*10+4 = 634
#define NBLK  (NCHUNK * B_)          // 2048
#define GROUPS 64

// d_ws layout (floats):
//   [0..31]      per-batch max of target (int-bits atomicMax; 0xAA poison is negative,
//                any positive-float bits win, so no pre-zeroing needed)
//   [64..1087]   64 partial-sum slots, stride 16 floats (64 B); zeroed by k_max blk 0
#define SLOT0 64
#define STRIDE 16

typedef float f2 __attribute__((ext_vector_type(2)));

__global__ __launch_bounds__(256) void k_max(const float* __restrict__ tgt,
                                             float* __restrict__ ws) {
    if (blockIdx.x == 0) {                     // zero slots (stream order vs k_ssim)
        for (int i = threadIdx.x; i < GROUPS * STRIDE; i += 256)
            ws[SLOT0 + i] = 0.0f;
    }
    const int b   = blockIdx.x >> 5;
    const int seg = blockIdx.x & 31;
    const int perseg = (H_ * W_) / 32;         // 7360 floats
    const float4* p = (const float4*)(tgt + (size_t)b * (H_ * W_) + (size_t)seg * perseg);
    const int n4 = perseg / 4;                 // 1840
    float m = 0.0f;
    for (int i = threadIdx.x; i < n4; i += 256) {
        float4 v = p[i];
        m = fmaxf(m, fmaxf(fmaxf(v.x, v.y), fmaxf(v.z, v.w)));
    }
    #pragma unroll
    for (int off = 32; off; off >>= 1)
        m = fmaxf(m, __shfl_down(m, off, 64));
    __shared__ float sm[4];
    const int lane = threadIdx.x & 63, wv = threadIdx.x >> 6;
    if (lane == 0) sm[wv] = m;
    __syncthreads();
    if (threadIdx.x == 0) {
        m = fmaxf(fmaxf(sm[0], sm[1]), fmaxf(sm[2], sm[3]));
        atomicMax((int*)ws + b, __float_as_int(m));   // inputs >= 0
    }
}

__device__ __forceinline__ void loadrow(const float* __restrict__ xr,
                                        const float* __restrict__ yr,
                                        f2 xn[4], f2 yn[4]) {
    const f2* xp = (const f2*)xr;   // (r*368 + 2t)*4 is always 8B-aligned
    const f2* yp = (const f2*)yr;
    xn[0] = xp[0]; xn[1] = xp[1]; xn[2] = xp[2]; xn[3] = xp[3];
    yn[0] = yp[0]; yn[1] = yp[1]; yn[2] = yp[2]; yn[3] = yp[3];
}

// Horizontal 7-sums for TWO adjacent windows (cols c..c+6, c+1..c+7) from
// preloaded registers.  h = {x0,x1, y0,y1, xx0,xx1, yy0,yy1, xy0,xy1}
__device__ __forceinline__ void hsum2v(const f2 xn[4], const f2 yn[4], float h[10]) {
    const float xs[8] = {xn[0].x, xn[0].y, xn[1].x, xn[1].y, xn[2].x, xn[2].y, xn[3].x, xn[3].y};
    const float ys[8] = {yn[0].x, yn[0].y, yn[1].x, yn[1].y, yn[2].x, yn[2].y, yn[3].x, yn[3].y};
    float hx = 0, hy = 0, hxx = 0, hyy = 0, hxy = 0;
    #pragma unroll
    for (int k = 0; k < 7; ++k) {
        const float xv = xs[k], yv = ys[k];
        hx += xv; hy += yv;
        hxx = fmaf(xv, xv, hxx);
        hyy = fmaf(yv, yv, hyy);
        hxy = fmaf(xv, yv, hxy);
    }
    h[0] = hx;  h[1] = hx - xs[0] + xs[7];
    h[2] = hy;  h[3] = hy - ys[0] + ys[7];
    h[4] = hxx; h[5] = fmaf(xs[7], xs[7], fmaf(-xs[0], xs[0], hxx));
    h[6] = hyy; h[7] = fmaf(ys[7], ys[7], fmaf(-ys[0], ys[0], hyy));
    h[8] = hxy; h[9] = fmaf(xs[7], ys[7], fmaf(-xs[0], ys[0], hxy));
}

__global__ __launch_bounds__(192, 4) void k_ssim(const float* __restrict__ X,
                                                 const float* __restrict__ Y,
                                                 float* __restrict__ ws) {
    const int t    = threadIdx.x;              // 0..191
    const int w    = t >> 6;
    const int lane = t & 63;
    const int b    = blockIdx.y;
    const int r0   = blockIdx.x * CHUNK;
    const int outRows = min(CHUNK, OH - r0);   // 10, or 4 for last chunk
    const int c    = 2 * t;                    // base output col
    const bool colOK = (c < OW);               // t <= 180

    const float dr  = ws[b];
    float C1 = 0.01f * dr; C1 *= C1;
    float C2 = 0.03f * dr; C2 *= C2;
    const float c1s = C1 * 2401.0f;            // scaled-domain constants (u* scale cancels)
    const float c2s = C2 * 2401.0f;
    const float covn2 = 2.0f * (49.0f / 48.0f);
    const float covn  = 49.0f / 48.0f;

    const float* xb = X + (size_t)b * (H_ * W_) + c;
    const float* yb = Y + (size_t)b * (H_ * W_) + c;

    float acc = 0.0f;

    if (colOK) {
        float ring[5][7][2];                   // [quantity][row slot][col]
        float tot[5][2] = {};
        float h[10];
        f2 xn[4], yn[4];

        #pragma unroll
        for (int p = 0; p < 6; ++p) {          // prime 6 halo rows
            loadrow(xb + (size_t)(r0 + p) * W_, yb + (size_t)(r0 + p) * W_, xn, yn);
            hsum2v(xn, yn, h);
            #pragma unroll
            for (int q = 0; q < 5; ++q) {
                ring[q][p][0] = h[2 * q];     ring[q][p][1] = h[2 * q + 1];
                tot[q][0] += h[2 * q];        tot[q][1] += h[2 * q + 1];
            }
        }
        loadrow(xb + (size_t)(r0 + 6) * W_, yb + (size_t)(r0 + 6) * W_, xn, yn);

        for (int ii = 0; ii < outRows; ii += 7) {
            #pragma unroll
            for (int p = 0; p < 7; ++p) {      // ring slot == p (compile-time)
                const int i = ii + p;
                if (i >= outRows) break;       // block-uniform
                hsum2v(xn, yn, h);             // consume prefetched row r0+i+6
                if (i + 1 < outRows)           // prefetch row r0+i+7 (covered by ~100 VALU below)
                    loadrow(xb + (size_t)(r0 + i + 7) * W_, yb + (size_t)(r0 + i + 7) * W_, xn, yn);

                #pragma unroll
                for (int q = 0; q < 5; ++q) {
                    tot[q][0] += h[2 * q];    tot[q][1] += h[2 * q + 1];
                }

                #pragma unroll
                for (int j = 0; j < 2; ++j) {
                    const float tx = tot[0][j], ty = tot[1][j];
                    const float txx = tot[2][j], tyy = tot[3][j], txy = tot[4][j];
                    const float pxy = tx * ty;
                    const float A1  = fmaf(pxy, 2.0f, c1s);
                    const float s2  = fmaf(tx, tx, ty * ty);
                    const float B1  = s2 + c1s;
                    const float mxy = fmaf(49.0f, txy, -pxy);
                    const float A2  = fmaf(covn2, mxy, c2s);
                    const float vs  = fmaf(49.0f, txx + tyy, -s2);
                    const float B2  = fmaf(covn, vs, c2s);
                    acc = fmaf(A1 * A2, __builtin_amdgcn_rcpf(B1 * B2), acc);
                }

                const int sn = (p + 6) % 7;    // retire slot p, insert new in slot sn
                #pragma unroll
                for (int q = 0; q < 5; ++q) {
                    tot[q][0] -= ring[q][p][0];  tot[q][1] -= ring[q][p][1];
                    ring[q][sn][0] = h[2 * q];   ring[q][sn][1] = h[2 * q + 1];
                }
            }
        }
    }

    // wave reduce, LDS across 3 waves, ONE scattered atomic per block. No fences.
    #pragma unroll
    for (int off = 32; off; off >>= 1)
        acc += __shfl_down(acc, off, 64);
    __shared__ float sm[3];
    if (lane == 0) sm[w] = acc;
    __syncthreads();
    if (t == 0) {
        const float s = sm[0] + sm[1] + sm[2];
        const int blk = blockIdx.y * NCHUNK + blockIdx.x;
        atomicAdd(ws + SLOT0 + (blk & (GROUPS - 1)) * STRIDE, s);  // 64 independent lines
    }
}

__global__ __launch_bounds__(64) void k_fin(const float* __restrict__ ws,
                                            float* __restrict__ out) {
    float v = ws[SLOT0 + threadIdx.x * STRIDE];   // kernel boundary orders prior atomics
    #pragma unroll
    for (int off = 32; off; off >>= 1)
        v += __shfl_down(v, off, 64);
    if (threadIdx.x == 0)
        out[0] = 1.0f - v * (1.0f / (32.0f * 634.0f * 362.0f));
}

extern "C" void kernel_launch(void* const* d_in, const int* in_sizes, int n_in,
                              void* d_out, int out_size, void* d_ws, size_t ws_size,
                              hipStream_t stream) {
    const float* X = (const float*)d_in[0];   // 'output'
    const float* Y = (const float*)d_in[1];   // 'target'
    float* ws = (float*)d_ws;

    k_max<<<dim3(1024), dim3(256), 0, stream>>>(Y, ws);
    k_ssim<<<dim3(NCHUNK, B_), dim3(192), 0, stream>>>(X, Y, ws);
    k_fin<<<dim3(1), dim3(64), 0, stream>>>(ws, (float*)d_out);
}

// Round 7
// 120.977 us; speedup vs baseline: 1.6440x; 1.3817x over previous
//
#include <hip/hip_runtime.h>

#define B_    32
#define H_    640
#define W_    368
#define OH    634          // H - 6
#define OW    362          // W - 6
#define CHUNK 10           // output rows per block
#define NCHUNK 64          // 63 full chunks + last (4 rows); 63*10+4 = 634
#define NBLK  (NCHUNK * B_)          // 2048
#define GROUPS 64

// d_ws layout (floats):
//   [0..31]      per-batch max of target (int-bits atomicMax; 0xAA poison is negative,
//                any positive-float bits win, so no pre-zeroing needed)
//   [64..1087]   64 partial-sum slots, stride 16 floats (64 B); zeroed by k_max blk 0
#define SLOT0 64
#define STRIDE 16

typedef float f2 __attribute__((ext_vector_type(2)));

__global__ __launch_bounds__(256) void k_max(const float* __restrict__ tgt,
                                             float* __restrict__ ws) {
    if (blockIdx.x == 0) {                     // zero slots (stream order vs k_ssim)
        for (int i = threadIdx.x; i < GROUPS * STRIDE; i += 256)
            ws[SLOT0 + i] = 0.0f;
    }
    const int b   = blockIdx.x >> 5;
    const int seg = blockIdx.x & 31;
    const int perseg = (H_ * W_) / 32;         // 7360 floats
    const float4* p = (const float4*)(tgt + (size_t)b * (H_ * W_) + (size_t)seg * perseg);
    const int n4 = perseg / 4;                 // 1840
    float m = 0.0f;
    for (int i = threadIdx.x; i < n4; i += 256) {
        float4 v = p[i];
        m = fmaxf(m, fmaxf(fmaxf(v.x, v.y), fmaxf(v.z, v.w)));
    }
    #pragma unroll
    for (int off = 32; off; off >>= 1)
        m = fmaxf(m, __shfl_down(m, off, 64));
    __shared__ float sm[4];
    const int lane = threadIdx.x & 63, wv = threadIdx.x >> 6;
    if (lane == 0) sm[wv] = m;
    __syncthreads();
    if (threadIdx.x == 0) {
        m = fmaxf(fmaxf(sm[0], sm[1]), fmaxf(sm[2], sm[3]));
        atomicMax((int*)ws + b, __float_as_int(m));   // inputs >= 0
    }
}

__device__ __forceinline__ void loadrow(const float* __restrict__ xr,
                                        const float* __restrict__ yr,
                                        f2 xn[4], f2 yn[4]) {
    const f2* xp = (const f2*)xr;   // (r*368 + 2t)*4 is always 8B-aligned
    const f2* yp = (const f2*)yr;
    xn[0] = xp[0]; xn[1] = xp[1]; xn[2] = xp[2]; xn[3] = xp[3];
    yn[0] = yp[0]; yn[1] = yp[1]; yn[2] = yp[2]; yn[3] = yp[3];
}

// Horizontal 7-sums for TWO adjacent windows (cols c..c+6, c+1..c+7) from
// preloaded registers.  h = {x0,x1, y0,y1, xx0,xx1, yy0,yy1, xy0,xy1}
__device__ __forceinline__ void hsum2v(const f2 xn[4], const f2 yn[4], float h[10]) {
    const float xs[8] = {xn[0].x, xn[0].y, xn[1].x, xn[1].y, xn[2].x, xn[2].y, xn[3].x, xn[3].y};
    const float ys[8] = {yn[0].x, yn[0].y, yn[1].x, yn[1].y, yn[2].x, yn[2].y, yn[3].x, yn[3].y};
    float hx = 0, hy = 0, hxx = 0, hyy = 0, hxy = 0;
    #pragma unroll
    for (int k = 0; k < 7; ++k) {
        const float xv = xs[k], yv = ys[k];
        hx += xv; hy += yv;
        hxx = fmaf(xv, xv, hxx);
        hyy = fmaf(yv, yv, hyy);
        hxy = fmaf(xv, yv, hxy);
    }
    h[0] = hx;  h[1] = hx - xs[0] + xs[7];
    h[2] = hy;  h[3] = hy - ys[0] + ys[7];
    h[4] = hxx; h[5] = fmaf(xs[7], xs[7], fmaf(-xs[0], xs[0], hxx));
    h[6] = hyy; h[7] = fmaf(ys[7], ys[7], fmaf(-ys[0], ys[0], hyy));
    h[8] = hxy; h[9] = fmaf(xs[7], ys[7], fmaf(-xs[0], ys[0], hxy));
}

// NOTE: no min-waves clamp! __launch_bounds__(192,4) forced VGPR=64 in R6 and the
// 70-reg ring spilled to scratch (WRITE_SIZE 96 KB -> 120 MB). Working set needs
// ~100 VGPRs; unconstrained alloc (R5) gave 84 with no spill.
__global__ __launch_bounds__(192) void k_ssim(const float* __restrict__ X,
                                              const float* __restrict__ Y,
                                              float* __restrict__ ws) {
    const int t    = threadIdx.x;              // 0..191
    const int w    = t >> 6;
    const int lane = t & 63;
    const int b    = blockIdx.y;
    const int r0   = blockIdx.x * CHUNK;
    const int outRows = min(CHUNK, OH - r0);   // 10, or 4 for last chunk
    const int c    = 2 * t;                    // base output col
    const bool colOK = (c < OW);               // t <= 180

    const float dr  = ws[b];
    float C1 = 0.01f * dr; C1 *= C1;
    float C2 = 0.03f * dr; C2 *= C2;
    const float c1s = C1 * 2401.0f;            // scaled-domain constants (u* scale cancels)
    const float c2s = C2 * 2401.0f;
    const float covn2 = 2.0f * (49.0f / 48.0f);
    const float covn  = 49.0f / 48.0f;

    const float* xb = X + (size_t)b * (H_ * W_) + c;
    const float* yb = Y + (size_t)b * (H_ * W_) + c;

    float acc = 0.0f;

    if (colOK) {
        float ring[5][7][2];                   // [quantity][row slot][col]
        float tot[5][2] = {};
        float h[10];
        f2 xn[4], yn[4];

        #pragma unroll
        for (int p = 0; p < 6; ++p) {          // prime 6 halo rows
            loadrow(xb + (size_t)(r0 + p) * W_, yb + (size_t)(r0 + p) * W_, xn, yn);
            hsum2v(xn, yn, h);
            #pragma unroll
            for (int q = 0; q < 5; ++q) {
                ring[q][p][0] = h[2 * q];     ring[q][p][1] = h[2 * q + 1];
                tot[q][0] += h[2 * q];        tot[q][1] += h[2 * q + 1];
            }
        }
        loadrow(xb + (size_t)(r0 + 6) * W_, yb + (size_t)(r0 + 6) * W_, xn, yn);

        for (int ii = 0; ii < outRows; ii += 7) {
            #pragma unroll
            for (int p = 0; p < 7; ++p) {      // ring slot == p (compile-time)
                const int i = ii + p;
                if (i >= outRows) break;       // block-uniform
                hsum2v(xn, yn, h);             // consume prefetched row r0+i+6
                if (i + 1 < outRows)           // prefetch row r0+i+7 (covered by ~100 VALU below)
                    loadrow(xb + (size_t)(r0 + i + 7) * W_, yb + (size_t)(r0 + i + 7) * W_, xn, yn);

                #pragma unroll
                for (int q = 0; q < 5; ++q) {
                    tot[q][0] += h[2 * q];    tot[q][1] += h[2 * q + 1];
                }

                #pragma unroll
                for (int j = 0; j < 2; ++j) {
                    const float tx = tot[0][j], ty = tot[1][j];
                    const float txx = tot[2][j], tyy = tot[3][j], txy = tot[4][j];
                    const float pxy = tx * ty;
                    const float A1  = fmaf(pxy, 2.0f, c1s);
                    const float s2  = fmaf(tx, tx, ty * ty);
                    const float B1  = s2 + c1s;
                    const float mxy = fmaf(49.0f, txy, -pxy);
                    const float A2  = fmaf(covn2, mxy, c2s);
                    const float vs  = fmaf(49.0f, txx + tyy, -s2);
                    const float B2  = fmaf(covn, vs, c2s);
                    acc = fmaf(A1 * A2, __builtin_amdgcn_rcpf(B1 * B2), acc);
                }

                const int sn = (p + 6) % 7;    // retire slot p, insert new in slot sn
                #pragma unroll
                for (int q = 0; q < 5; ++q) {
                    tot[q][0] -= ring[q][p][0];  tot[q][1] -= ring[q][p][1];
                    ring[q][sn][0] = h[2 * q];   ring[q][sn][1] = h[2 * q + 1];
                }
            }
        }
    }

    // wave reduce, LDS across 3 waves, ONE scattered atomic per block. No fences.
    #pragma unroll
    for (int off = 32; off; off >>= 1)
        acc += __shfl_down(acc, off, 64);
    __shared__ float sm[3];
    if (lane == 0) sm[w] = acc;
    __syncthreads();
    if (t == 0) {
        const float s = sm[0] + sm[1] + sm[2];
        const int blk = blockIdx.y * NCHUNK + blockIdx.x;
        atomicAdd(ws + SLOT0 + (blk & (GROUPS - 1)) * STRIDE, s);  // 64 independent lines
    }
}

__global__ __launch_bounds__(64) void k_fin(const float* __restrict__ ws,
                                            float* __restrict__ out) {
    float v = ws[SLOT0 + threadIdx.x * STRIDE];   // kernel boundary orders prior atomics
    #pragma unroll
    for (int off = 32; off; off >>= 1)
        v += __shfl_down(v, off, 64);
    if (threadIdx.x == 0)
        out[0] = 1.0f - v * (1.0f / (32.0f * 634.0f * 362.0f));
}

extern "C" void kernel_launch(void* const* d_in, const int* in_sizes, int n_in,
                              void* d_out, int out_size, void* d_ws, size_t ws_size,
                              hipStream_t stream) {
    const float* X = (const float*)d_in[0];   // 'output'
    const float* Y = (const float*)d_in[1];   // 'target'
    float* ws = (float*)d_ws;

    k_max<<<dim3(1024), dim3(256), 0, stream>>>(Y, ws);
    k_ssim<<<dim3(NCHUNK, B_), dim3(192), 0, stream>>>(X, Y, ws);
    k_fin<<<dim3(1), dim3(64), 0, stream>>>(ws, (float*)d_out);
}